// Round 8
// baseline (95.052 us; speedup 1.0000x reference)
//
#include <hip/hip_runtime.h>
#include <hip/hip_fp16.h>
#include <math.h>

// Chamfer distance, B=4, N=M=8192, D=3, fp32, via f16 MFMA — SYMMETRIC d^2.
//
// One v_mfma_f32_32x32x16_f16 per 32x32 tile computes FULL
//   d2 = a^2 + b^2 - 2 a.b
// by packing into the K=16 slots (A side | B side):
//  g0 k0-2 : h(-2a)xyz        | h(b)xyz           (hi*hi cross)
//     k3-5 : l(-2a)xyz*2^8    | h(b)xyz*2^-8      (lo*hi, scale-compensated)
//     k6   : h(a^2)           | 1
//     k7   : 1                | h(b^2)
//  g1 k8-10: h(-2a)xyz*2^-8   | l(b)xyz*2^8       (hi*lo)
//     k11  : l(a^2)           | 1
//     k12  : 1                | l(b^2)
//  dropped l*l ~2^-24; measured absmax 0.0 (threshold 9.47e-4).
//
// Row-min -> dir0 partials, col-min -> dir1 partials, one pass serves both.
// Round 8: occupancy push. MSLICES 16 (512-col slices, 2048 blocks), one
// col-tile (2 MFMAs) per iteration (live D-regs 32), LDS 18.5 KB (records
// 16 KB + colmin 2 KB + two-pass row-transpose aliasing records),
// __launch_bounds__(256,5) -> 5 waves/SIMD (was 4, LDS+VGPR capped).

#define BATCH   4
#define NPTS    8192
#define THREADS 256
#define NCHUNKS 32            // n-chunks of 256 rows
#define MSLICES 16            // m-slices of 512 cols
#define MSL     512
#define SC      256.0f
#define ISC     (1.0f/256.0f)
#define FLT_BIG 3.4e38f

typedef _Float16 half8 __attribute__((ext_vector_type(8)));
typedef float f32x16 __attribute__((ext_vector_type(16)));

union U4H8 { uint4 u; half8 h; };

__device__ __forceinline__ unsigned pk(__half lo, __half hi) {
    return (unsigned)__half_as_ushort(lo) | ((unsigned)__half_as_ushort(hi) << 16);
}
__device__ __forceinline__ unsigned enc_f32(float f) {
    unsigned b = __float_as_uint(f);
    return (b & 0x80000000u) ? ~b : (b | 0x80000000u);
}
__device__ __forceinline__ float dec_f32(unsigned k) {
    unsigned b = (k & 0x80000000u) ? (k & 0x7FFFFFFFu) : ~k;
    return __uint_as_float(b);
}

__global__ __launch_bounds__(THREADS, 5) void chamfer_mfma_kernel(
        const float* __restrict__ pc1, const float* __restrict__ pc2,
        float* __restrict__ part_row, float* __restrict__ part_col,
        float* __restrict__ out) {
    const int bid    = blockIdx.x;       // 2048 = batch*512 + nchunk*16 + mslice
    const int mslice = bid & 15;
    const int nchunk = (bid >> 4) & 31;
    const int batch  = bid >> 9;

    if (bid == 0 && threadIdx.x < BATCH) out[threadIdx.x] = 0.0f;

    // LDS dwords: [0..4095] B records (g0 at p*4, g1 at 2048+p*4);
    //             [0..4223] reused as per-wave row-transpose scratch (32x33 per wave);
    //             [4224..4735] colmin (ordered-uint).
    __shared__ unsigned smem[4736];
    unsigned* colmin = &smem[4224];

    const int t = threadIdx.x;
    const int L = t & 63;
    const int w = t >> 6;
    const int g = L >> 5;
    const __half one = __float2half(1.0f);
    const __half z0  = __float2half(0.0f);

    // ---- stage m-slice: 512 b-points -> packed B-fragment records ----
    const float* bb = pc2 + ((size_t)batch * NPTS + (size_t)mslice * MSL) * 3;
    #pragma unroll
    for (int k = 0; k < 2; ++k) {
        const int p = k * THREADS + t;
        const float x = bb[3 * p + 0], y = bb[3 * p + 1], z = bb[3 * p + 2];
        __half hx = __float2half(x), hy = __float2half(y), hz = __float2half(z);
        __half lx = __float2half((x - __half2float(hx)) * SC);
        __half ly = __float2half((y - __half2float(hy)) * SC);
        __half lz = __float2half((z - __half2float(hz)) * SC);
        __half sx = __float2half(__half2float(hx) * ISC);
        __half sy = __float2half(__half2float(hy) * ISC);
        __half sz = __float2half(__half2float(hz) * ISC);
        const float b2 = fmaf(x, x, fmaf(y, y, z * z));
        __half hb2 = __float2half(b2);
        __half lb2 = __float2half(b2 - __half2float(hb2));
        uint4* g0 = (uint4*)&smem[p * 4];
        uint4* g1 = (uint4*)&smem[2048 + p * 4];
        *g0 = make_uint4(pk(hx, hy), pk(hz, sx), pk(sy, sz), pk(one, hb2));
        *g1 = make_uint4(pk(lx, ly), pk(lz, one), pk(lb2, z0), pk(z0, z0));
    }
    // init colmin: 512 entries, 2 per thread
    colmin[t] = 0xFFFFFFFFu;
    colmin[THREADS + t] = 0xFFFFFFFFu;

    // ---- A fragments: 2 n-tiles per wave (rows nchunk*256 + w*64 + (L&31) + ti*32)
    U4H8 A[2];
    #pragma unroll
    for (int ti = 0; ti < 2; ++ti) {
        const int n = nchunk * 256 + w * 64 + (L & 31) + ti * 32;
        const float* ap = pc1 + ((size_t)batch * NPTS + n) * 3;
        const float x = ap[0], y = ap[1], z = ap[2];
        const float vx = -2.0f * x, vy = -2.0f * y, vz = -2.0f * z;
        __half Hx = __float2half(vx), Hy = __float2half(vy), Hz = __float2half(vz);
        __half Lx = __float2half((vx - __half2float(Hx)) * SC);
        __half Ly = __float2half((vy - __half2float(Hy)) * SC);
        __half Lz = __float2half((vz - __half2float(Hz)) * SC);
        __half Sx = __float2half(__half2float(Hx) * ISC);
        __half Sy = __float2half(__half2float(Hy) * ISC);
        __half Sz = __float2half(__half2float(Hz) * ISC);
        const float a2 = fmaf(x, x, fmaf(y, y, z * z));
        __half ha2 = __float2half(a2);
        __half la2 = __float2half(a2 - __half2float(ha2));
        if (g == 0) {
            A[ti].u = make_uint4(pk(Hx, Hy), pk(Hz, Lx), pk(Ly, Lz), pk(ha2, one));
        } else {
            A[ti].u = make_uint4(pk(Sx, Sy), pk(Sz, la2), pk(one, z0), pk(z0, z0));
        }
    }

    __syncthreads();

    // ---- main loop: 16 col-tiles, 2 MFMAs (both row-tiles) each ----
    const f32x16 zf = {0.0f};
    float rm0[16], rm1[16];
    #pragma unroll
    for (int r = 0; r < 16; ++r) { rm0[r] = FLT_BIG; rm1[r] = FLT_BIG; }

    const int rbase = g * 2048 + (L & 31) * 4;
    for (int mt = 0; mt < 16; ++mt) {
        U4H8 b;
        b.u = *(const uint4*)&smem[rbase + mt * 128];
        f32x16 d0 = __builtin_amdgcn_mfma_f32_32x32x16_f16(A[0].h, b.h, zf, 0, 0, 0);
        f32x16 d1 = __builtin_amdgcn_mfma_f32_32x32x16_f16(A[1].h, b.h, zf, 0, 0, 0);
        float c = FLT_BIG;
        #pragma unroll
        for (int r = 0; r < 16; ++r) {
            rm0[r] = fminf(rm0[r], d0[r]);
            rm1[r] = fminf(rm1[r], d1[r]);
            c = fminf(fminf(c, d0[r]), d1[r]);   // v_min3: col tree over both row-tiles
        }
        c = fminf(c, __shfl_xor(c, 32, 64));     // combine k-group row halves
        if (L < 32) atomicMin(&colmin[mt * 32 + L], enc_f32(c));
    }

    // one barrier: all ds_min done, all record reads done (scratch aliases records)
    __syncthreads();

    // ---- col partials (colmin region untouched by transpose scratch) ----
    #pragma unroll
    for (int i = 0; i < 2; ++i) {
        const int j = i * THREADS + t;
        part_col[((size_t)batch * NCHUNKS + nchunk) * NPTS + mslice * MSL + j] =
            dec_f32(colmin[j]);
    }

    // ---- row-min via two-pass per-wave LDS transpose (32 rows x stride 33) ----
    float* sf = (float*)smem;
    const int wbase = w * 1056;              // 32 * 33 per wave, disjoint regions
    const int row = L & 31, ch = L >> 5;
    const size_t prow_base = ((size_t)batch * MSLICES + mslice) * NPTS
                           + nchunk * 256 + w * 64;
    // pass 1: rm0 -> rows w*64 + 0..31
    #pragma unroll
    for (int r = 0; r < 16; ++r) {
        const int row0 = (r & 3) + 8 * (r >> 2) + 4 * g;
        sf[wbase + row0 * 33 + (L & 31)] = rm0[r];
    }
    {
        const float* rp = &sf[wbase + row * 33 + ch * 16];
        float v = rp[0];
        #pragma unroll
        for (int i = 1; i < 16; ++i) v = fminf(v, rp[i]);
        v = fminf(v, __shfl_xor(v, 32, 64));
        if (L < 32) part_row[prow_base + row] = v;
    }
    // pass 2: rm1 -> rows w*64 + 32..63 (same scratch; wave-internal ordering)
    #pragma unroll
    for (int r = 0; r < 16; ++r) {
        const int row0 = (r & 3) + 8 * (r >> 2) + 4 * g;
        sf[wbase + row0 * 33 + (L & 31)] = rm1[r];
    }
    {
        const float* rp = &sf[wbase + row * 33 + ch * 16];
        float v = rp[0];
        #pragma unroll
        for (int i = 1; i < 16; ++i) v = fminf(v, rp[i]);
        v = fminf(v, __shfl_xor(v, 32, 64));
        if (L < 32) part_row[prow_base + 32 + row] = v;
    }
}

__global__ __launch_bounds__(THREADS) void chamfer_reduce_kernel(
        const float* __restrict__ part_row, const float* __restrict__ part_col,
        float* __restrict__ out) {
    const int idx   = blockIdx.x * THREADS + threadIdx.x;   // 0..65535
    const int dir   = idx >> 15;
    const int batch = (idx >> 13) & 3;
    const int n     = idx & (NPTS - 1);

    float v = FLT_BIG;
    if (dir == 0) {
        const float* pb = part_row + (size_t)batch * MSLICES * NPTS + n;
        #pragma unroll
        for (int s = 0; s < MSLICES; ++s) v = fminf(v, pb[(size_t)s * NPTS]);
    } else {
        const float* pb = part_col + (size_t)batch * NCHUNKS * NPTS + n;
        #pragma unroll
        for (int s = 0; s < NCHUNKS; ++s) v = fminf(v, pb[(size_t)s * NPTS]);
    }
    float d2 = fmaxf(v, 0.0f);

    #pragma unroll
    for (int off = 32; off > 0; off >>= 1)
        d2 += __shfl_down(d2, off, 64);

    __shared__ float wsum[THREADS / 64];
    if ((threadIdx.x & 63) == 0) wsum[threadIdx.x >> 6] = d2;
    __syncthreads();

    if (threadIdx.x == 0) {
        float ssum = 0.0f;
        #pragma unroll
        for (int wv = 0; wv < THREADS / 64; ++wv) ssum += wsum[wv];
        atomicAdd(&out[batch], ssum * (1.0f / (float)NPTS));
    }
}

extern "C" void kernel_launch(void* const* d_in, const int* in_sizes, int n_in,
                              void* d_out, int out_size, void* d_ws, size_t ws_size,
                              hipStream_t stream) {
    const float* pc1 = (const float*)d_in[0];
    const float* pc2 = (const float*)d_in[1];
    float* out      = (float*)d_out;
    float* part_row = (float*)d_ws;                                   // 2 MB
    float* part_col = part_row + (size_t)BATCH * MSLICES * NPTS;      // 4 MB

    chamfer_mfma_kernel<<<BATCH * NCHUNKS * MSLICES, THREADS, 0, stream>>>(
        pc1, pc2, part_row, part_col, out);
    chamfer_reduce_kernel<<<(2 * BATCH * NPTS) / THREADS, THREADS, 0, stream>>>(
        part_row, part_col, out);
}

// Round 9
// 75.147 us; speedup vs baseline: 1.2649x; 1.2649x over previous
//
#include <hip/hip_runtime.h>
#include <hip/hip_fp16.h>
#include <math.h>

// Chamfer distance, B=4, N=M=8192, D=3, fp32, via f16 MFMA — SYMMETRIC d^2.
//
// One v_mfma_f32_32x32x16_f16 per 32x32 tile computes FULL
//   d2 = a^2 + b^2 - 2 a.b
// by packing into the K=16 slots (A side | B side):
//  g0 k0-2 : h(-2a)xyz        | h(b)xyz           (hi*hi cross)
//     k3-5 : l(-2a)xyz*2^8    | h(b)xyz*2^-8      (lo*hi, scale-compensated)
//     k6   : h(a^2)           | 1
//     k7   : 1                | h(b^2)
//  g1 k8-10: h(-2a)xyz*2^-8   | l(b)xyz*2^8       (hi*lo)
//     k11  : l(a^2)           | 1
//     k12  : 1                | l(b^2)
//  dropped l*l ~2^-24; measured absmax 0.0 (threshold 9.47e-4).
//
// Row-min -> dir0 partials, col-min -> dir1 partials, one pass serves both.
// Round 9 (R7 base; R8's launch_bounds AGPR-spill trap removed):
//  - NO __launch_bounds__ cap: accumulators must stay in VGPRs.
//  - per-iter __shfl_xor removed: both k-group half-lanes ds_min the same
//    colmin word (fire-and-forget, off the critical path).
//  - next B-fragment pair prefetched into regs (ds_read lands an iter early).
//  - col-tile pair processed sequentially: live D-regs 64 -> 32, each half's
//    min-tree overlaps the other half's MFMA latency.

#define BATCH   4
#define NPTS    8192
#define THREADS 256
#define NCHUNKS 32            // n-chunks of 256 rows
#define MSLICES 8             // m-slices of 1024 cols
#define MSL     1024
#define SC      256.0f
#define ISC     (1.0f/256.0f)
#define FLT_BIG 3.4e38f

typedef _Float16 half8 __attribute__((ext_vector_type(8)));
typedef float f32x16 __attribute__((ext_vector_type(16)));

union U4H8 { uint4 u; half8 h; };

__device__ __forceinline__ unsigned pk(__half lo, __half hi) {
    return (unsigned)__half_as_ushort(lo) | ((unsigned)__half_as_ushort(hi) << 16);
}
__device__ __forceinline__ unsigned enc_f32(float f) {
    unsigned b = __float_as_uint(f);
    return (b & 0x80000000u) ? ~b : (b | 0x80000000u);
}
__device__ __forceinline__ float dec_f32(unsigned k) {
    unsigned b = (k & 0x80000000u) ? (k & 0x7FFFFFFFu) : ~k;
    return __uint_as_float(b);
}

__global__ void chamfer_mfma_kernel(
        const float* __restrict__ pc1, const float* __restrict__ pc2,
        float* __restrict__ part_row, float* __restrict__ part_col,
        float* __restrict__ out) {
    const int bid    = blockIdx.x;       // 1024 = batch*256 + nchunk*8 + mslice
    const int mslice = bid & 7;
    const int nchunk = (bid >> 3) & 31;
    const int batch  = bid >> 8;

    if (bid == 0 && threadIdx.x < BATCH) out[threadIdx.x] = 0.0f;

    // LDS dwords: [0..8191] B records (g0 at p*4, g1 at 4096+p*4);
    //             [0..8447] reused as row-transpose scratch after the loop;
    //             [8448..9471] colmin (ordered-uint).
    __shared__ unsigned smem[9472];
    unsigned* colmin = &smem[8448];

    const int t = threadIdx.x;
    const int L = t & 63;
    const int w = t >> 6;
    const int g = L >> 5;
    const __half one = __float2half(1.0f);
    const __half z0  = __float2half(0.0f);

    // ---- stage m-slice: 1024 b-points -> packed B-fragment records ----
    const float* bb = pc2 + ((size_t)batch * NPTS + (size_t)mslice * MSL) * 3;
    #pragma unroll
    for (int k = 0; k < 4; ++k) {
        const int p = k * THREADS + t;
        const float x = bb[3 * p + 0], y = bb[3 * p + 1], z = bb[3 * p + 2];
        __half hx = __float2half(x), hy = __float2half(y), hz = __float2half(z);
        __half lx = __float2half((x - __half2float(hx)) * SC);
        __half ly = __float2half((y - __half2float(hy)) * SC);
        __half lz = __float2half((z - __half2float(hz)) * SC);
        __half sx = __float2half(__half2float(hx) * ISC);
        __half sy = __float2half(__half2float(hy) * ISC);
        __half sz = __float2half(__half2float(hz) * ISC);
        const float b2 = fmaf(x, x, fmaf(y, y, z * z));
        __half hb2 = __float2half(b2);
        __half lb2 = __float2half(b2 - __half2float(hb2));
        uint4* g0 = (uint4*)&smem[p * 4];
        uint4* g1 = (uint4*)&smem[4096 + p * 4];
        *g0 = make_uint4(pk(hx, hy), pk(hz, sx), pk(sy, sz), pk(one, hb2));
        *g1 = make_uint4(pk(lx, ly), pk(lz, one), pk(lb2, z0), pk(z0, z0));
    }
    // init colmin: 1024 entries, 4 per thread
    #pragma unroll
    for (int i = 0; i < 4; ++i) colmin[i * THREADS + t] = 0xFFFFFFFFu;

    // ---- A fragments: 2 n-tiles per wave (rows nchunk*256 + w*64 + (L&31) + ti*32)
    U4H8 A[2];
    #pragma unroll
    for (int ti = 0; ti < 2; ++ti) {
        const int n = nchunk * 256 + w * 64 + (L & 31) + ti * 32;
        const float* ap = pc1 + ((size_t)batch * NPTS + n) * 3;
        const float x = ap[0], y = ap[1], z = ap[2];
        const float vx = -2.0f * x, vy = -2.0f * y, vz = -2.0f * z;
        __half Hx = __float2half(vx), Hy = __float2half(vy), Hz = __float2half(vz);
        __half Lx = __float2half((vx - __half2float(Hx)) * SC);
        __half Ly = __float2half((vy - __half2float(Hy)) * SC);
        __half Lz = __float2half((vz - __half2float(Hz)) * SC);
        __half Sx = __float2half(__half2float(Hx) * ISC);
        __half Sy = __float2half(__half2float(Hy) * ISC);
        __half Sz = __float2half(__half2float(Hz) * ISC);
        const float a2 = fmaf(x, x, fmaf(y, y, z * z));
        __half ha2 = __float2half(a2);
        __half la2 = __float2half(a2 - __half2float(ha2));
        if (g == 0) {
            A[ti].u = make_uint4(pk(Hx, Hy), pk(Hz, Lx), pk(Ly, Lz), pk(ha2, one));
        } else {
            A[ti].u = make_uint4(pk(Sx, Sy), pk(Sz, la2), pk(one, z0), pk(z0, z0));
        }
    }

    __syncthreads();

    // ---- main loop: 32 m-tiles in pairs, halves processed sequentially ----
    const f32x16 zf = {0.0f};
    float rm0[16], rm1[16];
    #pragma unroll
    for (int r = 0; r < 16; ++r) { rm0[r] = FLT_BIG; rm1[r] = FLT_BIG; }

    const int rbase = g * 4096 + (L & 31) * 4;
    const int col = L & 31;
    U4H8 nb0, nb1;
    nb0.u = *(const uint4*)&smem[rbase];
    nb1.u = *(const uint4*)&smem[rbase + 128];
    for (int mt = 0; mt < 32; mt += 2) {
        const U4H8 b0 = nb0, b1 = nb1;
        if (mt + 2 < 32) {                       // prefetch next pair
            nb0.u = *(const uint4*)&smem[rbase + (mt + 2) * 128];
            nb1.u = *(const uint4*)&smem[rbase + (mt + 2) * 128 + 128];
        }
        // half 1: col-tile b0 (both row-tiles)
        {
            f32x16 d0 = __builtin_amdgcn_mfma_f32_32x32x16_f16(A[0].h, b0.h, zf, 0, 0, 0);
            f32x16 d1 = __builtin_amdgcn_mfma_f32_32x32x16_f16(A[1].h, b0.h, zf, 0, 0, 0);
            float c = FLT_BIG;
            #pragma unroll
            for (int r = 0; r < 16; ++r) {
                rm0[r] = fminf(rm0[r], d0[r]);
                rm1[r] = fminf(rm1[r], d1[r]);
                c = fminf(fminf(c, d0[r]), d1[r]);       // v_min3
            }
            atomicMin(&colmin[mt * 32 + col], enc_f32(c));   // all 64 lanes; 2-way same-addr
        }
        // half 2: col-tile b1
        {
            f32x16 d0 = __builtin_amdgcn_mfma_f32_32x32x16_f16(A[0].h, b1.h, zf, 0, 0, 0);
            f32x16 d1 = __builtin_amdgcn_mfma_f32_32x32x16_f16(A[1].h, b1.h, zf, 0, 0, 0);
            float c = FLT_BIG;
            #pragma unroll
            for (int r = 0; r < 16; ++r) {
                rm0[r] = fminf(rm0[r], d0[r]);
                rm1[r] = fminf(rm1[r], d1[r]);
                c = fminf(fminf(c, d0[r]), d1[r]);
            }
            atomicMin(&colmin[(mt + 1) * 32 + col], enc_f32(c));
        }
    }

    // ---- row-min cross-lane via padded LDS transpose (stride 33) ----
    __syncthreads();                     // records free, ds_min done
    float* sf = (float*)smem;
    const int wbase = w * 2112;          // 64 rows * 33
    #pragma unroll
    for (int r = 0; r < 16; ++r) {
        const int row0 = (r & 3) + 8 * (r >> 2) + 4 * g;
        sf[wbase + row0 * 33 + col] = rm0[r];
        sf[wbase + (row0 + 32) * 33 + col] = rm1[r];
    }
    __syncthreads();

    float v = FLT_BIG;
    const int rb = wbase + L * 33;
    #pragma unroll
    for (int i = 0; i < 32; ++i) v = fminf(v, sf[rb + i]);
    const int grow = nchunk * 256 + w * 64 + L;
    part_row[((size_t)batch * MSLICES + mslice) * NPTS + grow] = v;

    // ---- col partials ----
    #pragma unroll
    for (int i = 0; i < 4; ++i) {
        const int j = i * THREADS + t;
        part_col[((size_t)batch * NCHUNKS + nchunk) * NPTS + mslice * MSL + j] =
            dec_f32(colmin[j]);
    }
}

__global__ __launch_bounds__(THREADS) void chamfer_reduce_kernel(
        const float* __restrict__ part_row, const float* __restrict__ part_col,
        float* __restrict__ out) {
    const int idx   = blockIdx.x * THREADS + threadIdx.x;   // 0..65535
    const int dir   = idx >> 15;
    const int batch = (idx >> 13) & 3;
    const int n     = idx & (NPTS - 1);

    float v = FLT_BIG;
    if (dir == 0) {
        const float* pb = part_row + (size_t)batch * MSLICES * NPTS + n;
        #pragma unroll
        for (int s = 0; s < MSLICES; ++s) v = fminf(v, pb[(size_t)s * NPTS]);
    } else {
        const float* pb = part_col + (size_t)batch * NCHUNKS * NPTS + n;
        #pragma unroll
        for (int s = 0; s < NCHUNKS; ++s) v = fminf(v, pb[(size_t)s * NPTS]);
    }
    float d2 = fmaxf(v, 0.0f);

    #pragma unroll
    for (int off = 32; off > 0; off >>= 1)
        d2 += __shfl_down(d2, off, 64);

    __shared__ float wsum[THREADS / 64];
    if ((threadIdx.x & 63) == 0) wsum[threadIdx.x >> 6] = d2;
    __syncthreads();

    if (threadIdx.x == 0) {
        float ssum = 0.0f;
        #pragma unroll
        for (int wv = 0; wv < THREADS / 64; ++wv) ssum += wsum[wv];
        atomicAdd(&out[batch], ssum * (1.0f / (float)NPTS));
    }
}

extern "C" void kernel_launch(void* const* d_in, const int* in_sizes, int n_in,
                              void* d_out, int out_size, void* d_ws, size_t ws_size,
                              hipStream_t stream) {
    const float* pc1 = (const float*)d_in[0];
    const float* pc2 = (const float*)d_in[1];
    float* out      = (float*)d_out;
    float* part_row = (float*)d_ws;                                   // 1 MB
    float* part_col = part_row + (size_t)BATCH * MSLICES * NPTS;      // 4 MB

    chamfer_mfma_kernel<<<BATCH * NCHUNKS * MSLICES, THREADS, 0, stream>>>(
        pc1, pc2, part_row, part_col, out);
    chamfer_reduce_kernel<<<(2 * BATCH * NPTS) / THREADS, THREADS, 0, stream>>>(
        part_row, part_col, out);
}